// Round 14
// baseline (370.036 us; speedup 1.0000x reference)
//
#include <hip/hip_runtime.h>
#include <hip/hip_cooperative_groups.h>
#include <stdint.h>

namespace cg = cooperative_groups;

static constexpr int B = 32, S = 2048, F = 768;
static constexpr int CS = 64;            // rows per chunk
static constexpr int NCH = S / CS;       // 32 chunks per batch
static constexpr int F4 = F / 4;         // 192 (row stride in float4/int4)
static constexpr int FT = F4;            // 192 threads, 4 features each
static constexpr int NPAIR = B * NCH;    // 1024 chunks

typedef float v4f __attribute__((ext_vector_type(4)));
typedef int   v4i __attribute__((ext_vector_type(4)));
typedef unsigned int v4u __attribute__((ext_vector_type(4)));

__device__ __forceinline__ v4f mk4(float a, float b, float c, float d) {
    v4f v; v.x = a; v.y = b; v.z = c; v.w = d; return v;
}

// ================= Cooperative single kernel =================
// Phase 1: flip-copy own chunk + build own bitwords (kept in registers, also
//          stored nt for neighbors). grid.sync(). Phase 2: fwd+bwd deltas.
__global__ __launch_bounds__(FT, 4) void coopK(const v4i* __restrict__ masks,
                                               const v4f* __restrict__ x,
                                               const float* __restrict__ ts,
                                               uint32_t* __restrict__ bwLo,
                                               uint32_t* __restrict__ bwHi,
                                               float* __restrict__ out) {
    const int pair = blockIdx.x;             // b*NCH + c
    const int b = pair >> 5, c = pair & 31;
    const int g0 = c * CS;
    const int j = threadIdx.x;
    const size_t N4 = (size_t)B * S * F4;
    const float* tsb = ts + (size_t)b * S;

    __shared__ float tss[CS];
    if (j < CS) tss[j] = tsb[g0 + j];

    // ---- Phase 1a: flip-copy 64 rows: o2[b,g0+k,:] = x[b,S-1-g0-k,:]
    const v4f* xb = x + (size_t)b * S * F4 + j;
    v4f* o2 = reinterpret_cast<v4f*>(out) + 2 * N4 + (size_t)(b * S + g0) * F4 + j;
    #pragma unroll 8
    for (int k = 0; k < CS; ++k) {
        __builtin_nontemporal_store(
            __builtin_nontemporal_load(&xb[(size_t)(S - 1 - g0 - k) * F4]),
            &o2[(size_t)k * F4]);
    }

    // ---- Phase 1b: bitwords for own 64 rows (stay in registers)
    const v4i* mp = masks + (size_t)(b * S + g0) * F4 + j;
    uint32_t a0 = 0, a1 = 0, a2 = 0, a3 = 0;   // rows [0,32)
    uint32_t c0 = 0, c1 = 0, c2 = 0, c3 = 0;   // rows [32,64)
    #pragma unroll
    for (int g = 0; g < 8; ++g) {
        v4i mv[8];
        #pragma unroll
        for (int q = 0; q < 8; ++q) mv[q] = __builtin_nontemporal_load(&mp[(size_t)(g * 8 + q) * F4]);
        #pragma unroll
        for (int q = 0; q < 8; ++q) {
            const int k = g * 8 + q;
            const uint32_t bit = 1u << (k & 31);
            if (k < 32) {
                if (mv[q].x) a0 |= bit;
                if (mv[q].y) a1 |= bit;
                if (mv[q].z) a2 |= bit;
                if (mv[q].w) a3 |= bit;
            } else {
                if (mv[q].x) c0 |= bit;
                if (mv[q].y) c1 |= bit;
                if (mv[q].z) c2 |= bit;
                if (mv[q].w) c3 |= bit;
            }
        }
    }
    {
        v4u wl; wl.x = a0; wl.y = a1; wl.z = a2; wl.w = a3;
        v4u wh; wh.x = c0; wh.y = c1; wh.z = c2; wh.w = c3;
        __builtin_nontemporal_store(wl, reinterpret_cast<v4u*>(bwLo + ((size_t)pair * F + 4 * j)));
        __builtin_nontemporal_store(wh, reinterpret_cast<v4u*>(bwHi + ((size_t)pair * F + 4 * j)));
    }

    cg::this_grid().sync();

    // ---- Phase 2: carries from neighbor bitwords, then pure-store delta loops
    uint32_t alo[4] = {a0, a1, a2, a3};
    uint32_t ahi[4] = {c0, c1, c2, c3};
    float p[4], n[4];
    {
        float def = tsb[0];
        p[0] = p[1] = p[2] = p[3] = def;
        uint32_t need = 0xFu;
        for (int d = c - 1; d >= 0 && need; --d) {
            v4u ul = *reinterpret_cast<const v4u*>(bwLo + ((size_t)(b * NCH + d) * F + 4 * j));
            v4u uh = *reinterpret_cast<const v4u*>(bwHi + ((size_t)(b * NCH + d) * F + 4 * j));
            uint32_t lo[4] = {ul.x, ul.y, ul.z, ul.w};
            uint32_t hi[4] = {uh.x, uh.y, uh.z, uh.w};
            const int base = d * CS;
            #pragma unroll
            for (int i = 0; i < 4; ++i) if (need & (1u << i)) {
                if (hi[i])      { p[i] = tsb[base + 32 + (31 - __clz((int)hi[i]))]; need &= ~(1u << i); }
                else if (lo[i]) { p[i] = tsb[base +      (31 - __clz((int)lo[i]))]; need &= ~(1u << i); }
            }
        }
    }
    {
        float def = tsb[S - 1];
        n[0] = n[1] = n[2] = n[3] = def;
        uint32_t need = 0xFu;
        for (int d = c + 1; d < NCH && need; ++d) {
            v4u ul = *reinterpret_cast<const v4u*>(bwLo + ((size_t)(b * NCH + d) * F + 4 * j));
            v4u uh = *reinterpret_cast<const v4u*>(bwHi + ((size_t)(b * NCH + d) * F + 4 * j));
            uint32_t lo[4] = {ul.x, ul.y, ul.z, ul.w};
            uint32_t hi[4] = {uh.x, uh.y, uh.z, uh.w};
            const int base = d * CS;
            #pragma unroll
            for (int i = 0; i < 4; ++i) if (need & (1u << i)) {
                if (lo[i])      { n[i] = tsb[base +      (__ffs((int)lo[i]) - 1)]; need &= ~(1u << i); }
                else if (hi[i]) { n[i] = tsb[base + 32 + (__ffs((int)hi[i]) - 1)]; need &= ~(1u << i); }
            }
        }
    }

    // forward-delta stores
    v4f* o0 = reinterpret_cast<v4f*>(out) + (size_t)(b * S + g0) * F4 + j;
    #pragma unroll
    for (int k = 0; k < 32; ++k) {
        float t = tss[k];
        __builtin_nontemporal_store(mk4(t - p[0], t - p[1], t - p[2], t - p[3]), &o0[(size_t)k * F4]);
        const uint32_t bit = 1u << k;
        #pragma unroll
        for (int i = 0; i < 4; ++i) if (alo[i] & bit) p[i] = t;
    }
    #pragma unroll
    for (int k = 32; k < 64; ++k) {
        float t = tss[k];
        __builtin_nontemporal_store(mk4(t - p[0], t - p[1], t - p[2], t - p[3]), &o0[(size_t)k * F4]);
        const uint32_t bit = 1u << (k - 32);
        #pragma unroll
        for (int i = 0; i < 4; ++i) if (ahi[i] & bit) p[i] = t;
    }

    // backward-delta stores, FLIPPED coords
    v4f* o1b = reinterpret_cast<v4f*>(out) + N4 + (size_t)b * S * F4 + j;
    #pragma unroll
    for (int k = 63; k >= 32; --k) {
        float t = tss[k];
        size_t fr = (size_t)(S - 1 - g0 - k) * F4;
        __builtin_nontemporal_store(mk4(n[0] - t, n[1] - t, n[2] - t, n[3] - t), &o1b[fr]);
        const uint32_t bit = 1u << (k - 32);
        #pragma unroll
        for (int i = 0; i < 4; ++i) if (ahi[i] & bit) n[i] = t;
    }
    #pragma unroll
    for (int k = 31; k >= 0; --k) {
        float t = tss[k];
        size_t fr = (size_t)(S - 1 - g0 - k) * F4;
        __builtin_nontemporal_store(mk4(n[0] - t, n[1] - t, n[2] - t, n[3] - t), &o1b[fr]);
        const uint32_t bit = 1u << k;
        #pragma unroll
        for (int i = 0; i < 4; ++i) if (alo[i] & bit) n[i] = t;
    }
}

// ================= Fallback path (proven 194 µs, R11 structure) =================
__global__ __launch_bounds__(FT) void passA(const v4i* __restrict__ masks,
                                            uint32_t* __restrict__ bwLo,
                                            uint32_t* __restrict__ bwHi) {
    const int hb = blockIdx.x;
    const int pair = hb >> 1, half = hb & 1;
    const int b = pair >> 5, c = pair & 31;
    const int j = threadIdx.x;
    const int r0 = c * CS + half * 32;
    const v4i* mp = masks + (size_t)(b * S + r0) * F4 + j;
    uint32_t w0 = 0, w1 = 0, w2 = 0, w3 = 0;
    #pragma unroll
    for (int g = 0; g < 4; ++g) {
        v4i mv[8];
        #pragma unroll
        for (int q = 0; q < 8; ++q) mv[q] = __builtin_nontemporal_load(&mp[(size_t)(g * 8 + q) * F4]);
        #pragma unroll
        for (int q = 0; q < 8; ++q) {
            const uint32_t bit = 1u << (g * 8 + q);
            if (mv[q].x) w0 |= bit;
            if (mv[q].y) w1 |= bit;
            if (mv[q].z) w2 |= bit;
            if (mv[q].w) w3 |= bit;
        }
    }
    v4u w; w.x = w0; w.y = w1; w.z = w2; w.w = w3;
    uint32_t* base = half ? bwHi : bwLo;
    *reinterpret_cast<v4u*>(base + (size_t)pair * F + 4 * j) = w;
}

__global__ __launch_bounds__(FT) void passC(const float* __restrict__ ts,
                                            const uint32_t* __restrict__ bwLo,
                                            const uint32_t* __restrict__ bwHi,
                                            float* __restrict__ out) {
    const int blk = blockIdx.x;
    const bool bwd = blk >= NPAIR;
    const int pair = bwd ? blk - NPAIR : blk;
    const int b = pair >> 5, c = pair & 31;
    const int g0 = c * CS;
    const int j = threadIdx.x;
    const size_t N4 = (size_t)B * S * F4;
    const float* tsb = ts + (size_t)b * S;

    __shared__ float tss[CS];
    if (j < CS) tss[j] = tsb[g0 + j];
    __syncthreads();

    v4u lo4 = *reinterpret_cast<const v4u*>(bwLo + (size_t)pair * F + 4 * j);
    v4u hi4 = *reinterpret_cast<const v4u*>(bwHi + (size_t)pair * F + 4 * j);
    uint32_t alo[4] = {lo4.x, lo4.y, lo4.z, lo4.w};
    uint32_t ahi[4] = {hi4.x, hi4.y, hi4.z, hi4.w};

    if (!bwd) {
        float p[4];
        float def = tsb[0];
        p[0] = p[1] = p[2] = p[3] = def;
        uint32_t need = 0xFu;
        for (int d = c - 1; d >= 0 && need; --d) {
            v4u ul = *reinterpret_cast<const v4u*>(bwLo + (size_t)(b * NCH + d) * F + 4 * j);
            v4u uh = *reinterpret_cast<const v4u*>(bwHi + (size_t)(b * NCH + d) * F + 4 * j);
            uint32_t lo[4] = {ul.x, ul.y, ul.z, ul.w};
            uint32_t hi[4] = {uh.x, uh.y, uh.z, uh.w};
            const int base = d * CS;
            #pragma unroll
            for (int i = 0; i < 4; ++i) if (need & (1u << i)) {
                if (hi[i])      { p[i] = tsb[base + 32 + (31 - __clz((int)hi[i]))]; need &= ~(1u << i); }
                else if (lo[i]) { p[i] = tsb[base +      (31 - __clz((int)lo[i]))]; need &= ~(1u << i); }
            }
        }
        v4f* o0 = reinterpret_cast<v4f*>(out) + (size_t)(b * S + g0) * F4 + j;
        #pragma unroll
        for (int k = 0; k < 32; ++k) {
            float t = tss[k];
            __builtin_nontemporal_store(mk4(t - p[0], t - p[1], t - p[2], t - p[3]), &o0[(size_t)k * F4]);
            const uint32_t bit = 1u << k;
            #pragma unroll
            for (int i = 0; i < 4; ++i) if (alo[i] & bit) p[i] = t;
        }
        #pragma unroll
        for (int k = 32; k < 64; ++k) {
            float t = tss[k];
            __builtin_nontemporal_store(mk4(t - p[0], t - p[1], t - p[2], t - p[3]), &o0[(size_t)k * F4]);
            const uint32_t bit = 1u << (k - 32);
            #pragma unroll
            for (int i = 0; i < 4; ++i) if (ahi[i] & bit) p[i] = t;
        }
    } else {
        float n[4];
        float def = tsb[S - 1];
        n[0] = n[1] = n[2] = n[3] = def;
        uint32_t need = 0xFu;
        for (int d = c + 1; d < NCH && need; ++d) {
            v4u ul = *reinterpret_cast<const v4u*>(bwLo + (size_t)(b * NCH + d) * F + 4 * j);
            v4u uh = *reinterpret_cast<const v4u*>(bwHi + (size_t)(b * NCH + d) * F + 4 * j);
            uint32_t lo[4] = {ul.x, ul.y, ul.z, ul.w};
            uint32_t hi[4] = {uh.x, uh.y, uh.z, uh.w};
            const int base = d * CS;
            #pragma unroll
            for (int i = 0; i < 4; ++i) if (need & (1u << i)) {
                if (lo[i])      { n[i] = tsb[base +      (__ffs((int)lo[i]) - 1)]; need &= ~(1u << i); }
                else if (hi[i]) { n[i] = tsb[base + 32 + (__ffs((int)hi[i]) - 1)]; need &= ~(1u << i); }
            }
        }
        v4f* o1b = reinterpret_cast<v4f*>(out) + N4 + (size_t)b * S * F4 + j;
        #pragma unroll
        for (int k = 63; k >= 32; --k) {
            float t = tss[k];
            size_t fr = (size_t)(S - 1 - g0 - k) * F4;
            __builtin_nontemporal_store(mk4(n[0] - t, n[1] - t, n[2] - t, n[3] - t), &o1b[fr]);
            const uint32_t bit = 1u << (k - 32);
            #pragma unroll
            for (int i = 0; i < 4; ++i) if (ahi[i] & bit) n[i] = t;
        }
        #pragma unroll
        for (int k = 31; k >= 0; --k) {
            float t = tss[k];
            size_t fr = (size_t)(S - 1 - g0 - k) * F4;
            __builtin_nontemporal_store(mk4(n[0] - t, n[1] - t, n[2] - t, n[3] - t), &o1b[fr]);
            const uint32_t bit = 1u << k;
            #pragma unroll
            for (int i = 0; i < 4; ++i) if (alo[i] & bit) n[i] = t;
        }
    }
}

static constexpr int CPY_BLOCKS = 2048;
__global__ __launch_bounds__(256) void copyK(const v4f* __restrict__ x,
                                             v4f* __restrict__ o2) {
    const size_t N4 = (size_t)B * S * F4;
    const size_t stride = (size_t)CPY_BLOCKS * 256;
    for (size_t i = (size_t)blockIdx.x * 256 + threadIdx.x; i < N4; i += stride) {
        size_t row = i / F4;
        size_t f   = i - row * F4;
        size_t t   = row & (S - 1);
        size_t src = (row - t + (S - 1 - t)) * F4 + f;
        __builtin_nontemporal_store(__builtin_nontemporal_load(&x[src]), &o2[i]);
    }
}

extern "C" void kernel_launch(void* const* d_in, const int* in_sizes, int n_in,
                              void* d_out, int out_size, void* d_ws, size_t ws_size,
                              hipStream_t stream) {
    const float* ts    = (const float*)d_in[0];
    const v4f* x       = (const v4f*)d_in[1];
    const v4i* masks   = (const v4i*)d_in[2];
    float* out = (float*)d_out;
    const size_t N4 = (size_t)B * S * F4;
    const size_t plane_words = (size_t)NPAIR * F;                 // 786432
    const size_t bw_bytes = 2 * plane_words * sizeof(uint32_t);   // 6.3 MB

    if (ws_size >= bw_bytes) {
        uint32_t* bwLo = (uint32_t*)d_ws;
        uint32_t* bwHi = bwLo + plane_words;
        void* args[] = {(void*)&masks, (void*)&x, (void*)&ts,
                        (void*)&bwLo, (void*)&bwHi, (void*)&out};
        hipError_t e = hipLaunchCooperativeKernel((const void*)coopK, dim3(NPAIR), dim3(FT),
                                                  args, 0, stream);
        if (e == hipSuccess) return;
        // cooperative launch unavailable -> proven 3-kernel path
        passA<<<2 * NPAIR, FT, 0, stream>>>(masks, bwLo, bwHi);
        passC<<<2 * NPAIR, FT, 0, stream>>>(ts, bwLo, bwHi, out);
        copyK<<<CPY_BLOCKS, 256, 0, stream>>>(x, reinterpret_cast<v4f*>(out) + 2 * N4);
        return;
    }
    // no workspace: single fused probe-style kernel would be needed; use
    // minimal-dependency fallback (copy + on-the-fly probes) — reuse passC-free path.
    // (ws is known-present in this harness; keep a safe simple fallback.)
    copyK<<<CPY_BLOCKS, 256, 0, stream>>>(x, reinterpret_cast<v4f*>(out) + 2 * N4);
}

// Round 15
// 193.591 us; speedup vs baseline: 1.9114x; 1.9114x over previous
//
#include <hip/hip_runtime.h>
#include <stdint.h>

static constexpr int B = 32, S = 2048, F = 768;
static constexpr int CS = 64;            // rows per chunk
static constexpr int NCH = S / CS;       // 32 chunks per batch
static constexpr int F4 = F / 4;         // 192 (row stride in float4/int4)
static constexpr int FT = F4;            // 192 threads, 4 features each

typedef float v4f __attribute__((ext_vector_type(4)));
typedef int   v4i __attribute__((ext_vector_type(4)));
typedef unsigned int v4u __attribute__((ext_vector_type(4)));

__device__ __forceinline__ v4f mk4(float a, float b, float c, float d) {
    v4f v; v.x = a; v.y = b; v.z = c; v.w = d; return v;
}

// ---------------- passA: masks -> 64-bit obs words per (b,chunk,feature) ----
// layout: bw[((blk*F + f)*2 + w)]  w=0: rows k<32 (bit k), w=1: rows k>=32.
__global__ __launch_bounds__(FT) void passA(const v4i* __restrict__ masks,
                                            uint32_t* __restrict__ bw) {
    const int blk = blockIdx.x;              // b*NCH + c
    const int b = blk >> 5, c = blk & 31;
    const int j = threadIdx.x;
    const v4i* mp = masks + (size_t)(b * S + c * CS) * F4 + j;
    uint32_t a0 = 0, a1 = 0, a2 = 0, a3 = 0;   // rows 0..31
    uint32_t c0 = 0, c1 = 0, c2 = 0, c3 = 0;   // rows 32..63
    #pragma unroll
    for (int g = 0; g < 8; ++g) {
        v4i mv[8];
        #pragma unroll
        for (int q = 0; q < 8; ++q) mv[q] = __builtin_nontemporal_load(&mp[(size_t)(g * 8 + q) * F4]);
        #pragma unroll
        for (int q = 0; q < 8; ++q) {
            const int k = g * 8 + q;
            const uint32_t bit = 1u << (k & 31);
            if (k < 32) {
                if (mv[q].x) a0 |= bit;
                if (mv[q].y) a1 |= bit;
                if (mv[q].z) a2 |= bit;
                if (mv[q].w) a3 |= bit;
            } else {
                if (mv[q].x) c0 |= bit;
                if (mv[q].y) c1 |= bit;
                if (mv[q].z) c2 |= bit;
                if (mv[q].w) c3 |= bit;
            }
        }
    }
    v4u w0; w0.x = a0; w0.y = c0; w0.z = a1; w0.w = c1;   // (lo,hi) f, f+1
    v4u w1; w1.x = a2; w1.y = c2; w1.z = a3; w1.w = c3;   // (lo,hi) f+2, f+3
    v4u* dst = reinterpret_cast<v4u*>(bw + ((size_t)blk * F + 4 * j) * 2);
    dst[0] = w0;
    dst[1] = w1;
}

// ---------------- passC: carries from neighbor bitwords + pure-store delta loops
__global__ __launch_bounds__(FT) void passC(const float* __restrict__ ts,
                                            const uint32_t* __restrict__ bw,
                                            float* __restrict__ out) {
    const int blk = blockIdx.x;              // b*NCH + c
    const int b = blk >> 5, c = blk & 31;
    const int g0 = c * CS;
    const int j = threadIdx.x;
    const size_t N4 = (size_t)B * S * F4;
    const float* tsb = ts + (size_t)b * S;

    __shared__ float tss[CS];
    if (j < CS) tss[j] = tsb[g0 + j];
    __syncthreads();

    // own bitwords
    const v4u* own = reinterpret_cast<const v4u*>(bw + ((size_t)blk * F + 4 * j) * 2);
    v4u w0 = own[0], w1 = own[1];
    uint32_t alo[4] = {w0.x, w0.z, w1.x, w1.z};
    uint32_t ahi[4] = {w0.y, w0.w, w1.y, w1.w};

    // forward carries: ts of last obs at row < g0 (virtual obs at row 0)
    float p[4], n[4];
    {
        float def = tsb[0];
        p[0] = p[1] = p[2] = p[3] = def;
        uint32_t need = 0xFu;
        for (int d = c - 1; d >= 0 && need; --d) {
            const v4u* nb = reinterpret_cast<const v4u*>(bw + ((size_t)(b * NCH + d) * F + 4 * j) * 2);
            v4u u0 = nb[0], u1 = nb[1];
            uint32_t lo[4] = {u0.x, u0.z, u1.x, u1.z};
            uint32_t hi[4] = {u0.y, u0.w, u1.y, u1.w};
            const int base = d * CS;
            #pragma unroll
            for (int i = 0; i < 4; ++i) if (need & (1u << i)) {
                if (hi[i])      { p[i] = tsb[base + 32 + (31 - __clz((int)hi[i]))]; need &= ~(1u << i); }
                else if (lo[i]) { p[i] = tsb[base +      (31 - __clz((int)lo[i]))]; need &= ~(1u << i); }
            }
        }
    }
    // backward carries: ts of first obs at row >= g0+CS (virtual obs at row S-1)
    {
        float def = tsb[S - 1];
        n[0] = n[1] = n[2] = n[3] = def;
        uint32_t need = 0xFu;
        for (int d = c + 1; d < NCH && need; ++d) {
            const v4u* nb = reinterpret_cast<const v4u*>(bw + ((size_t)(b * NCH + d) * F + 4 * j) * 2);
            v4u u0 = nb[0], u1 = nb[1];
            uint32_t lo[4] = {u0.x, u0.z, u1.x, u1.z};
            uint32_t hi[4] = {u0.y, u0.w, u1.y, u1.w};
            const int base = d * CS;
            #pragma unroll
            for (int i = 0; i < 4; ++i) if (need & (1u << i)) {
                if (lo[i])      { n[i] = tsb[base +      (__ffs((int)lo[i]) - 1)]; need &= ~(1u << i); }
                else if (hi[i]) { n[i] = tsb[base + 32 + (__ffs((int)hi[i]) - 1)]; need &= ~(1u << i); }
            }
        }
    }

    // forward-delta stores (nontemporal, bit-driven carries)
    v4f* o0 = reinterpret_cast<v4f*>(out) + (size_t)(b * S + g0) * F4 + j;
    #pragma unroll
    for (int k = 0; k < 32; ++k) {
        float t = tss[k];
        __builtin_nontemporal_store(mk4(t - p[0], t - p[1], t - p[2], t - p[3]), &o0[(size_t)k * F4]);
        const uint32_t bit = 1u << k;
        #pragma unroll
        for (int i = 0; i < 4; ++i) if (alo[i] & bit) p[i] = t;
    }
    #pragma unroll
    for (int k = 32; k < 64; ++k) {
        float t = tss[k];
        __builtin_nontemporal_store(mk4(t - p[0], t - p[1], t - p[2], t - p[3]), &o0[(size_t)k * F4]);
        const uint32_t bit = 1u << (k - 32);
        #pragma unroll
        for (int i = 0; i < 4; ++i) if (ahi[i] & bit) p[i] = t;
    }

    // backward-delta stores, FLIPPED coords: out1[b, S-1-(g0+k), :] = n - ts[g0+k]
    v4f* o1b = reinterpret_cast<v4f*>(out) + N4 + (size_t)b * S * F4 + j;
    #pragma unroll
    for (int k = 63; k >= 32; --k) {
        float t = tss[k];
        size_t fr = (size_t)(S - 1 - g0 - k) * F4;
        __builtin_nontemporal_store(mk4(n[0] - t, n[1] - t, n[2] - t, n[3] - t), &o1b[fr]);
        const uint32_t bit = 1u << (k - 32);
        #pragma unroll
        for (int i = 0; i < 4; ++i) if (ahi[i] & bit) n[i] = t;
    }
    #pragma unroll
    for (int k = 31; k >= 0; --k) {
        float t = tss[k];
        size_t fr = (size_t)(S - 1 - g0 - k) * F4;
        __builtin_nontemporal_store(mk4(n[0] - t, n[1] - t, n[2] - t, n[3] - t), &o1b[fr]);
        const uint32_t bit = 1u << k;
        #pragma unroll
        for (int i = 0; i < 4; ++i) if (alo[i] & bit) n[i] = t;
    }
}

// ---------------- Flat flip-copy kernel (fill-shaped): o2[i] = x[flip(i)] ----
static constexpr int CPY_BLOCKS = 2048;
__global__ __launch_bounds__(256) void copyK(const v4f* __restrict__ x,
                                             v4f* __restrict__ o2) {
    const size_t N4 = (size_t)B * S * F4;
    const size_t stride = (size_t)CPY_BLOCKS * 256;
    for (size_t i = (size_t)blockIdx.x * 256 + threadIdx.x; i < N4; i += stride) {
        size_t row = i / F4;                 // b*S + t
        size_t f   = i - row * F4;
        size_t t   = row & (S - 1);          // S power of 2
        size_t src = (row - t + (S - 1 - t)) * F4 + f;
        __builtin_nontemporal_store(__builtin_nontemporal_load(&x[src]), &o2[i]);
    }
}

// ---------------- Fallback (ws too small): probe kernel ----
__global__ __launch_bounds__(FT) void deltaProbeK(const float* __restrict__ ts,
                                                  const int4* __restrict__ masks,
                                                  float* __restrict__ out) {
    const int pair = blockIdx.x;
    const int b = pair >> 5, sc = pair & 31;
    const int g0 = sc * CS;
    const int j = threadIdx.x;
    const size_t N4 = (size_t)B * S * F4;
    const float* tsb = ts + (size_t)b * S;
    const int4* mbase = masks + (size_t)b * S * F4 + j;
    __shared__ float tss[CS];
    if (j < CS) tss[j] = tsb[g0 + j];
    __syncthreads();
    uint32_t a0 = 0, a1 = 0, a2 = 0, a3 = 0, c0 = 0, c1 = 0, c2 = 0, c3 = 0;
    #pragma unroll
    for (int g = 0; g < 8; ++g) {
        int4 mv[8];
        #pragma unroll
        for (int q = 0; q < 8; ++q) mv[q] = mbase[(size_t)(g0 + g * 8 + q) * F4];
        #pragma unroll
        for (int q = 0; q < 8; ++q) {
            const int k = g * 8 + q;
            const uint32_t bit = 1u << (k & 31);
            if (k < 32) { if (mv[q].x) a0 |= bit; if (mv[q].y) a1 |= bit; if (mv[q].z) a2 |= bit; if (mv[q].w) a3 |= bit; }
            else        { if (mv[q].x) c0 |= bit; if (mv[q].y) c1 |= bit; if (mv[q].z) c2 |= bit; if (mv[q].w) c3 |= bit; }
        }
    }
    float t0v = tsb[0];
    float p0 = t0v, p1 = t0v, p2 = t0v, p3 = t0v;
    if (g0 > 0) {
        unsigned um = 0xFu; int r = g0 - 1;
        while (um && r >= 0) {
            int rl = (r - 7 > 0) ? r - 7 : 0; int nn = r - rl + 1;
            int4 mv[8];
            #pragma unroll
            for (int q = 0; q < 8; ++q) if (q < nn) mv[q] = mbase[(size_t)(r - q) * F4];
            #pragma unroll
            for (int q = 0; q < 8; ++q) if (q < nn) {
                float t = tsb[r - q];
                if ((um & 1u) && mv[q].x) { p0 = t; um &= ~1u; }
                if ((um & 2u) && mv[q].y) { p1 = t; um &= ~2u; }
                if ((um & 4u) && mv[q].z) { p2 = t; um &= ~4u; }
                if ((um & 8u) && mv[q].w) { p3 = t; um &= ~8u; }
            }
            r = rl - 1;
        }
    }
    float tev = tsb[S - 1];
    float n0 = tev, n1 = tev, n2 = tev, n3 = tev;
    if (g0 + CS < S) {
        unsigned um = 0xFu; int r = g0 + CS;
        while (um && r < S) {
            int rh = (r + 7 < S - 1) ? r + 7 : S - 1; int nn = rh - r + 1;
            int4 mv[8];
            #pragma unroll
            for (int q = 0; q < 8; ++q) if (q < nn) mv[q] = mbase[(size_t)(r + q) * F4];
            #pragma unroll
            for (int q = 0; q < 8; ++q) if (q < nn) {
                float t = tsb[r + q];
                if ((um & 1u) && mv[q].x) { n0 = t; um &= ~1u; }
                if ((um & 2u) && mv[q].y) { n1 = t; um &= ~2u; }
                if ((um & 4u) && mv[q].z) { n2 = t; um &= ~4u; }
                if ((um & 8u) && mv[q].w) { n3 = t; um &= ~8u; }
            }
            r = rh + 1;
        }
    }
    v4f* o0 = reinterpret_cast<v4f*>(out) + (size_t)(b * S + g0) * F4 + j;
    #pragma unroll
    for (int k = 0; k < 32; ++k) {
        float t = tss[k];
        __builtin_nontemporal_store(mk4(t - p0, t - p1, t - p2, t - p3), &o0[(size_t)k * F4]);
        const uint32_t bit = 1u << k;
        if (a0 & bit) p0 = t; if (a1 & bit) p1 = t; if (a2 & bit) p2 = t; if (a3 & bit) p3 = t;
    }
    #pragma unroll
    for (int k = 32; k < 64; ++k) {
        float t = tss[k];
        __builtin_nontemporal_store(mk4(t - p0, t - p1, t - p2, t - p3), &o0[(size_t)k * F4]);
        const uint32_t bit = 1u << (k - 32);
        if (c0 & bit) p0 = t; if (c1 & bit) p1 = t; if (c2 & bit) p2 = t; if (c3 & bit) p3 = t;
    }
    v4f* o1b = reinterpret_cast<v4f*>(out) + N4 + (size_t)b * S * F4 + j;
    #pragma unroll
    for (int k = 63; k >= 32; --k) {
        float t = tss[k];
        size_t fr = (size_t)(S - 1 - g0 - k) * F4;
        __builtin_nontemporal_store(mk4(n0 - t, n1 - t, n2 - t, n3 - t), &o1b[fr]);
        const uint32_t bit = 1u << (k - 32);
        if (c0 & bit) n0 = t; if (c1 & bit) n1 = t; if (c2 & bit) n2 = t; if (c3 & bit) n3 = t;
    }
    #pragma unroll
    for (int k = 31; k >= 0; --k) {
        float t = tss[k];
        size_t fr = (size_t)(S - 1 - g0 - k) * F4;
        __builtin_nontemporal_store(mk4(n0 - t, n1 - t, n2 - t, n3 - t), &o1b[fr]);
        const uint32_t bit = 1u << k;
        if (a0 & bit) n0 = t; if (a1 & bit) n1 = t; if (a2 & bit) n2 = t; if (a3 & bit) n3 = t;
    }
}

extern "C" void kernel_launch(void* const* d_in, const int* in_sizes, int n_in,
                              void* d_out, int out_size, void* d_ws, size_t ws_size,
                              hipStream_t stream) {
    const float* ts    = (const float*)d_in[0];
    const v4f* x       = (const v4f*)d_in[1];
    float* out = (float*)d_out;
    const size_t N4 = (size_t)B * S * F4;
    const size_t bw_bytes = (size_t)B * NCH * F * 2 * sizeof(uint32_t);   // 6.3 MB

    if (ws_size >= bw_bytes) {
        uint32_t* bw = (uint32_t*)d_ws;
        passA<<<B * NCH, FT, 0, stream>>>((const v4i*)d_in[2], bw);
        passC<<<B * NCH, FT, 0, stream>>>(ts, bw, out);
    } else {
        deltaProbeK<<<B * NCH, FT, 0, stream>>>(ts, (const int4*)d_in[2], out);
    }
    copyK<<<CPY_BLOCKS, 256, 0, stream>>>(x, reinterpret_cast<v4f*>(out) + 2 * N4);
}